// Round 7
// baseline (454.387 us; speedup 1.0000x reference)
//
#include <hip/hip_runtime.h>
#include <stdint.h>

// Problem constants: x [B=2, S=4096, K=4096] -> M = 8192; weight [N=4096, K=4096]
#define M_DIM 8192
#define N_DIM 4096
#define K_DIM 4096

using int4v  = __attribute__((ext_vector_type(4))) int;
using int16v = __attribute__((ext_vector_type(16))) int;

// ---------------------------------------------------------------------------
// Pack kernel: int32 (widened int8 in [-127,127]) -> int8 bytes.
// ---------------------------------------------------------------------------
__global__ __launch_bounds__(256) void pack_kernel(const int4* __restrict__ sx,
                                                   const int4* __restrict__ sw,
                                                   unsigned int* __restrict__ dst,
                                                   int nx, int ntot) {
    int idx = blockIdx.x * blockDim.x + threadIdx.x;
    if (idx >= ntot) return;
    int4 v = (idx < nx) ? sx[idx] : sw[idx - nx];
    dst[idx] = (v.x & 0xff) | ((v.y & 0xff) << 8) | ((v.z & 0xff) << 16) |
               ((v.w & 0xff) << 24);
}

// ---------------------------------------------------------------------------
// Async global -> LDS copy, 16 B per lane (global_load_lds_dwordx4).
// ---------------------------------------------------------------------------
__device__ __forceinline__ void async_copy16(const char* g, char* l) {
    __builtin_amdgcn_global_load_lds(
        (const __attribute__((address_space(1))) char*)g,
        (__attribute__((address_space(3))) char*)l, 16, 0, 0);
}

// ---------------------------------------------------------------------------
// 256x256 i8 GEMM with mfma_i32_32x32x32_i8 (r7).
// Base = r2 (best measured: whole-tile compiler-scheduled body, one barrier
// pair per K-tile, square XCD chunks). Changes:
//  1. MFMA shape 16x16x64 -> 32x32x32: +12% rate ceiling (4404 vs 3944
//     TOPS), HALF the MFMA instructions per wave (32 vs 64; same 24
//     ds_read_b128), and full-128B-line epilogue stores (C/D col=lane&31 ->
//     32 consecutive int32 per store row vs 16 before).
//  2. Wave-parity de-phasing: even waves compute M-half 0 then 1, odd waves
//     1 then 0 -- staggers LDS-read bursts against MFMA bursts across the
//     2 waves/SIMD without barriers (both paths fully static indexing).
// ds_read bank note: 32-lane column reads alias 4 lanes per 16-B slot-group,
// but b128's byte-floor (1024 B / 128 B-per-cyc = 8 cyc) already covers the
// 4-way slot serialization when all 8 groups are hit (our swizzle does) ->
// time-neutral; SQ_LDS_BANK_CONFLICT may show counts, ignore.
//
// 512 threads = 8 waves (2M x 4N); wave tile 128x64 = 4x2 grid of 32x32
// MFMA tiles, BK = 128 B (4 k-substeps of 32). LDS: 2 dbuf x (A 32K + B
// 32K) = 128 KiB -> 1 block/CU.
//
// A/B operand layout (32x32x32 i8): m(or n) = lane&31, k = (lane>>5)*16 +
// byte 0..15 (4 VGPRs). C/D: col = lane&31, row = (reg&3) + 8*(reg>>2) +
// 4*(lane>>5) [m74/m101, dtype-independent].
//
// LDS swizzle (verified family): 16-B chunk (row, cg) stored at
// cg ^ ((row>>1)&7); global source pre-swizzled, reads XOR-correct.
// ---------------------------------------------------------------------------
__global__ __launch_bounds__(512, 2) void gemm_i8_kernel(
    const char* __restrict__ Aq,   // [M, K] int8
    const char* __restrict__ Bq,   // [N, K] int8
    const int* __restrict__ bias,  // [N] int32 (widened int8)
    const float* __restrict__ a_ptr,
    const float* __restrict__ b_ptr,
    int32_t* __restrict__ out)     // [M, N] int32 holding int8 values
{
    __shared__ char As0[256 * 128];   // 32 KiB each
    __shared__ char As1[256 * 128];
    __shared__ char Bs0[256 * 128];
    __shared__ char Bs1[256 * 128];

    const int tid  = threadIdx.x;
    const int lane = tid & 63;
    const int wave = tid >> 6;
    const int wr   = wave >> 2;   // 0..1 -> 128 M-rows
    const int wc   = wave & 3;    // 0..3 -> 64 N-cols

    // Square XCD chunks (r2-measured FETCH ~99 MB): 512 blocks = 8 XCDs x 64;
    // per XCD 8 M-tiles x 8 N-tiles -> A 8 MB + B 8 MB footprint.
    const int bid = blockIdx.x;
    const int xcd = bid & 7;
    const int lin = bid >> 3;                       // 0..63
    const int tile_m = (xcd & 3) * 8 + (lin & 7);   // 0..31
    const int tile_n = (xcd >> 2) * 8 + (lin >> 3); // 0..15
    const int m0 = tile_m * 256;
    const int n0 = tile_n * 256;

    const float alpha = *a_ptr;
    const float beta  = *b_ptr;

    int16v acc[4][2] = {};   // 128 accumulator regs

    // Fragment read coords (32x32x32): m/n = lane&31, k-group = lane>>5.
    const int al  = lane & 31;
    const int kg  = lane >> 5;
    const int key = (al >> 1) & 7;                  // swizzle key (row>>1)&7
    int koff[4];
#pragma unroll
    for (int ks = 0; ks < 4; ++ks)
        koff[ks] = ((ks * 2 + kg) ^ key) << 4;      // swizzled 16-B col offset
    const int abase = (wr * 128 + al) * 128;        // mt=0 row byte offset
    const int bbase = (wc * 64 + al) * 128;         // nt=0 row byte offset

    // Staging (identical to r2/r6, verified): thread t owns chunks c = t and
    // c = t+512 of each 128-row half (row = c>>3, stored cg = c&7, global
    // cg = (c&7) ^ ((c>>4)&7) = (c&7) ^ ((row>>1)&7)).
    const int srow = tid >> 3;                               // 0..63
    const int scg  = ((tid & 7) ^ ((tid >> 4) & 7)) << 4;    // byte col offset
    const char* gA0 = Aq + (size_t)(m0 + srow) * K_DIM + scg;
    const char* gA1 = gA0 + (size_t)64 * K_DIM;
    const char* gB0 = Bq + (size_t)(n0 + srow) * K_DIM + scg;
    const char* gB1 = gB0 + (size_t)64 * K_DIM;

#define STAGE_TILE(AS, BS, t)                                                \
    {                                                                        \
        const size_t offL = (size_t)(t) * 128;                               \
        const size_t offH = (size_t)128 * K_DIM + (size_t)(t) * 128;         \
        async_copy16(gA0 + offL, &AS[(tid << 4)]);                           \
        async_copy16(gA1 + offL, &AS[(tid << 4) + 8192]);                    \
        async_copy16(gA0 + offH, &AS[16384 + (tid << 4)]);                   \
        async_copy16(gA1 + offH, &AS[16384 + (tid << 4) + 8192]);            \
        async_copy16(gB0 + offL, &BS[(tid << 4)]);                           \
        async_copy16(gB1 + offL, &BS[(tid << 4) + 8192]);                    \
        async_copy16(gB0 + offH, &BS[16384 + (tid << 4)]);                   \
        async_copy16(gB1 + offH, &BS[16384 + (tid << 4) + 8192]);            \
    }

#define LOAD_A(AS, AF, mt)                                                   \
    _Pragma("unroll") for (int ks = 0; ks < 4; ++ks)                         \
        AF[ks] = *(const int4v*)&AS[abase + (mt)*4096 + koff[ks]];

#define LOAD_B(BS, BF, nt)                                                   \
    _Pragma("unroll") for (int ks = 0; ks < 4; ++ks)                         \
        BF[ks] = *(const int4v*)&BS[bbase + (nt)*4096 + koff[ks]];

    // ks-outer: 4 consecutive MFMAs are all independent (acc chains length 4,
    // separated by 4 instructions) -- good latency cover at 2 waves/SIMD.
#define MMH(mlo, A0, A1)                                                     \
    {                                                                        \
        __builtin_amdgcn_s_setprio(1);                                       \
        _Pragma("unroll") for (int ks = 0; ks < 4; ++ks) {                   \
            acc[(mlo)][0] = __builtin_amdgcn_mfma_i32_32x32x32_i8(           \
                A0[ks], bf0[ks], acc[(mlo)][0], 0, 0, 0);                    \
            acc[(mlo)][1] = __builtin_amdgcn_mfma_i32_32x32x32_i8(           \
                A0[ks], bf1[ks], acc[(mlo)][1], 0, 0, 0);                    \
            acc[(mlo) + 1][0] = __builtin_amdgcn_mfma_i32_32x32x32_i8(       \
                A1[ks], bf0[ks], acc[(mlo) + 1][0], 0, 0, 0);                \
            acc[(mlo) + 1][1] = __builtin_amdgcn_mfma_i32_32x32x32_i8(       \
                A1[ks], bf1[ks], acc[(mlo) + 1][1], 0, 0, 0);                \
        }                                                                    \
        __builtin_amdgcn_s_setprio(0);                                       \
    }

    // Wave-parity de-phased tile body: 8 B-reads + 2x(8 A-reads + 16 MFMA).
#define COMPUTE_TILE(AS, BS)                                                 \
    {                                                                        \
        int4v bf0[4], bf1[4];                                                \
        LOAD_B(BS, bf0, 0);                                                  \
        LOAD_B(BS, bf1, 1);                                                  \
        if (wave & 1) {                                                      \
            {                                                                \
                int4v a0[4], a1[4];                                          \
                LOAD_A(AS, a0, 2); LOAD_A(AS, a1, 3);                        \
                MMH(2, a0, a1);                                              \
            }                                                                \
            {                                                                \
                int4v a0[4], a1[4];                                          \
                LOAD_A(AS, a0, 0); LOAD_A(AS, a1, 1);                        \
                MMH(0, a0, a1);                                              \
            }                                                                \
        } else {                                                             \
            {                                                                \
                int4v a0[4], a1[4];                                          \
                LOAD_A(AS, a0, 0); LOAD_A(AS, a1, 1);                        \
                MMH(0, a0, a1);                                              \
            }                                                                \
            {                                                                \
                int4v a0[4], a1[4];                                          \
                LOAD_A(AS, a0, 2); LOAD_A(AS, a1, 3);                        \
                MMH(2, a0, a1);                                              \
            }                                                                \
        }                                                                    \
    }

#define TILE_END                                                             \
    {                                                                        \
        asm volatile("s_waitcnt vmcnt(0)" ::: "memory");                     \
        __builtin_amdgcn_s_barrier();                                        \
        __builtin_amdgcn_sched_barrier(0);                                   \
    }

    // Prologue: stage tile 0 into buf0 (latency exposed once).
    STAGE_TILE(As0, Bs0, 0);
    TILE_END;

#pragma unroll 1
    for (int it = 0; it < 15; ++it) {
        STAGE_TILE(As1, Bs1, 2 * it + 1);
        __builtin_amdgcn_sched_barrier(0);   // pin stage issue before compute
        COMPUTE_TILE(As0, Bs0);
        TILE_END;
        STAGE_TILE(As0, Bs0, 2 * it + 2);
        __builtin_amdgcn_sched_barrier(0);
        COMPUTE_TILE(As1, Bs1);
        TILE_END;
    }
    // Tile 30 (buf0): stage final tile 31 -> buf1.
    STAGE_TILE(As1, Bs1, 31);
    __builtin_amdgcn_sched_barrier(0);
    COMPUTE_TILE(As0, Bs0);
    TILE_END;
    // Tile 31 (buf1): compute only.
    COMPUTE_TILE(As1, Bs1);

    // Epilogue: C/D layout col = lane&31, row = (reg&3) + 8*(reg>>2) +
    // 4*(lane>>5). Each reg-quad writes 4 rows x 32 consecutive int32 =
    // full 128-B lines per row.
    const int obr = kg * 4;
#pragma unroll
    for (int nt = 0; nt < 2; ++nt) {
        const int gn = n0 + wc * 64 + nt * 32 + al;
        const float bb = beta * (float)bias[gn];
#pragma unroll
        for (int mt = 0; mt < 4; ++mt) {
            const int gmb = m0 + wr * 128 + mt * 32 + obr;
#pragma unroll
            for (int reg = 0; reg < 16; ++reg) {
                const int gm = gmb + (reg & 3) + 8 * (reg >> 2);
                float v = alpha * (float)acc[mt][nt][reg] + bb;
                v = rintf(v);                       // round half-to-even (numpy)
                v = fminf(fmaxf(v, -128.0f), 127.0f);
                out[(size_t)gm * N_DIM + gn] = (int32_t)v;
            }
        }
    }
}

// ---------------------------------------------------------------------------
extern "C" void kernel_launch(void* const* d_in, const int* in_sizes, int n_in,
                              void* d_out, int out_size, void* d_ws, size_t ws_size,
                              hipStream_t stream) {
    const int*   x    = (const int*)d_in[0];    // [M, K] widened int8
    const int*   w    = (const int*)d_in[1];    // [N, K] widened int8
    const int*   bias = (const int*)d_in[2];    // [N]
    const float* a    = (const float*)d_in[3];  // alpha scalar
    const float* b    = (const float*)d_in[4];  // beta scalar
    int32_t*     out  = (int32_t*)d_out;        // [M, N]

    char* xq = (char*)d_ws;                     // 32 MiB packed x
    const int nx   = (M_DIM * K_DIM) / 4;       // int4-groups in x
    const int nw   = (N_DIM * K_DIM) / 4;
    const int ntot = nx + nw;
    pack_kernel<<<(ntot + 255) / 256, 256, 0, stream>>>(
        (const int4*)x, (const int4*)w, (unsigned int*)xq, nx, ntot);

    char* wq = xq + (size_t)M_DIM * K_DIM;      // 16 MiB packed weight

    dim3 grid((M_DIM / 256) * (N_DIM / 256));   // 512 blocks, 1D for XCD swizzle
    gemm_i8_kernel<<<grid, 512, 0, stream>>>(xq, wq, bias, a, b, out);
}

// Round 8
// 398.790 us; speedup vs baseline: 1.1394x; 1.1394x over previous
//
#include <hip/hip_runtime.h>
#include <stdint.h>

// Problem constants: x [B=2, S=4096, K=4096] -> M = 8192; weight [N=4096, K=4096]
#define M_DIM 8192
#define N_DIM 4096
#define K_DIM 4096

using int4v = __attribute__((ext_vector_type(4))) int;

// ---------------------------------------------------------------------------
// Pack kernel: int32 (widened int8 in [-127,127]) -> int8 bytes.
// ---------------------------------------------------------------------------
__global__ __launch_bounds__(256) void pack_kernel(const int4* __restrict__ sx,
                                                   const int4* __restrict__ sw,
                                                   unsigned int* __restrict__ dst,
                                                   int nx, int ntot) {
    int idx = blockIdx.x * blockDim.x + threadIdx.x;
    if (idx >= ntot) return;
    int4 v = (idx < nx) ? sx[idx] : sw[idx - nx];
    dst[idx] = (v.x & 0xff) | ((v.y & 0xff) << 8) | ((v.z & 0xff) << 16) |
               ((v.w & 0xff) << 24);
}

// ---------------------------------------------------------------------------
// Async global -> LDS copy, 16 B per lane (global_load_lds_dwordx4).
// ---------------------------------------------------------------------------
__device__ __forceinline__ void async_copy16(const char* g, char* l) {
    __builtin_amdgcn_global_load_lds(
        (const __attribute__((address_space(1))) char*)g,
        (__attribute__((address_space(3))) char*)l, 16, 0, 0);
}

// ---------------------------------------------------------------------------
// 256x256 i8 GEMM = r2 base + T19 sched_group_barrier interleave (r8).
// R0-R7 post-mortem: every schedule/occupancy variant lands at per-K-tile
// time == MFMA pipe (2613 cyc) + LDS pipe (~2800 cyc) SERIALLY. Untested
// lever: per-wave ISSUE ORDER. r2's burst loads (16-read head) keep the
// LDS pipe busy while the matrix pipe idles, then vice versa. This round
// forces a compile-time {1 ds_read : 2 MFMA} interleave via T19
// sched_group_barrier so both pipes run concurrently within each wave.
// Tile body restructured by k-substep so the interleave is dependency-
// feasible: [12 reads ks0][12 reads ks1][32 MFMA ks0][32 MFMA ks1] --
// ks1 reads are independent of ks0 MFMAs and slot between them.
//
// Everything else is r2 verbatim: 512 thr = 8 waves (2M x 4N), wave tile
// 128x64 (8x4 of 16x16x64 MFMA), BK=128B, dbuf 128 KiB LDS, one barrier
// pair + vmcnt(0) per K-tile (stages issued at top -> ~full-tile slack),
// square XCD chunks (FETCH ~99 MB), verified swizzle (0 conflicts).
// ---------------------------------------------------------------------------
__global__ __launch_bounds__(512, 2) void gemm_i8_kernel(
    const char* __restrict__ Aq,   // [M, K] int8
    const char* __restrict__ Bq,   // [N, K] int8
    const int* __restrict__ bias,  // [N] int32 (widened int8)
    const float* __restrict__ a_ptr,
    const float* __restrict__ b_ptr,
    int32_t* __restrict__ out)     // [M, N] int32 holding int8 values
{
    __shared__ char As0[256 * 128];   // 32 KiB each
    __shared__ char As1[256 * 128];
    __shared__ char Bs0[256 * 128];
    __shared__ char Bs1[256 * 128];

    const int tid  = threadIdx.x;
    const int lane = tid & 63;
    const int wave = tid >> 6;
    const int wr   = wave >> 2;   // 0..1 -> 128 M-rows
    const int wc   = wave & 3;    // 0..3 -> 64 N-cols

    // Square XCD chunks (r2-measured FETCH ~99 MB): 512 blocks = 8 XCDs x 64;
    // per XCD 8 M-tiles x 8 N-tiles -> A 8 MB + B 8 MB footprint.
    const int bid = blockIdx.x;
    const int xcd = bid & 7;
    const int lin = bid >> 3;                       // 0..63
    const int tile_m = (xcd & 3) * 8 + (lin & 7);   // 0..31
    const int tile_n = (xcd >> 2) * 8 + (lin >> 3); // 0..15
    const int m0 = tile_m * 256;
    const int n0 = tile_n * 256;

    const float alpha = *a_ptr;
    const float beta  = *b_ptr;

    int4v acc[8][4] = {};   // 128 accumulator regs (AGPR)

    // Fragment read coords: lane holds op row m = lane&15, k-group = lane>>4.
    const int fr = lane & 15;
    const int gw = lane >> 4;
    const int swz = (fr >> 1) & 7;
    const int k0off = (gw ^ swz) << 4;          // k-substep 0
    const int k1off = ((4 + gw) ^ swz) << 4;    // k-substep 1
    const int arow = wr * 128 + fr;
    const int brow = wc * 64 + fr;

    // Staging: thread t owns chunks c = t and c = t+512 of each 128-row half
    // (row = c>>3, stored col-group = c&7, global cg = (c&7) ^ ((c>>4)&7)).
    const int srow = tid >> 3;                               // 0..63
    const int scg  = ((tid & 7) ^ ((tid >> 4) & 7)) << 4;    // byte col offset
    const char* gA0 = Aq + (size_t)(m0 + srow) * K_DIM + scg;
    const char* gA1 = gA0 + (size_t)64 * K_DIM;
    const char* gB0 = Bq + (size_t)(n0 + srow) * K_DIM + scg;
    const char* gB1 = gB0 + (size_t)64 * K_DIM;

#define STAGE_TILE(AS, BS, t)                                                \
    {                                                                        \
        const size_t offL = (size_t)(t) * 128;                               \
        const size_t offH = (size_t)128 * K_DIM + (size_t)(t) * 128;         \
        async_copy16(gA0 + offL, &AS[(tid << 4)]);                           \
        async_copy16(gA1 + offL, &AS[(tid << 4) + 8192]);                    \
        async_copy16(gA0 + offH, &AS[16384 + (tid << 4)]);                   \
        async_copy16(gA1 + offH, &AS[16384 + (tid << 4) + 8192]);            \
        async_copy16(gB0 + offL, &BS[(tid << 4)]);                           \
        async_copy16(gB1 + offL, &BS[(tid << 4) + 8192]);                    \
        async_copy16(gB0 + offH, &BS[16384 + (tid << 4)]);                   \
        async_copy16(gB1 + offH, &BS[16384 + (tid << 4) + 8192]);            \
    }

    // Tile body: loads split by k-substep so ks1 reads are independent of
    // ks0 MFMAs (interleave-feasible); SGB pattern pins the mix.
#define COMPUTE_TILE(AS, BS)                                                 \
    {                                                                        \
        int4v a0[8], b0[4], a1[8], b1[4];                                    \
        _Pragma("unroll") for (int i = 0; i < 8; ++i)                        \
            a0[i] = *(const int4v*)&AS[(arow + i * 16) * 128 + k0off];       \
        _Pragma("unroll") for (int j = 0; j < 4; ++j)                        \
            b0[j] = *(const int4v*)&BS[(brow + j * 16) * 128 + k0off];       \
        _Pragma("unroll") for (int i = 0; i < 8; ++i)                        \
            a1[i] = *(const int4v*)&AS[(arow + i * 16) * 128 + k1off];       \
        _Pragma("unroll") for (int j = 0; j < 4; ++j)                        \
            b1[j] = *(const int4v*)&BS[(brow + j * 16) * 128 + k1off];       \
        __builtin_amdgcn_s_setprio(1);                                       \
        _Pragma("unroll") for (int i = 0; i < 8; ++i)                        \
        _Pragma("unroll") for (int j = 0; j < 4; ++j)                        \
            acc[i][j] = __builtin_amdgcn_mfma_i32_16x16x64_i8(               \
                a0[i], b0[j], acc[i][j], 0, 0, 0);                           \
        _Pragma("unroll") for (int i = 0; i < 8; ++i)                        \
        _Pragma("unroll") for (int j = 0; j < 4; ++j)                        \
            acc[i][j] = __builtin_amdgcn_mfma_i32_16x16x64_i8(               \
                a1[i], b1[j], acc[i][j], 0, 0, 0);                           \
        __builtin_amdgcn_s_setprio(0);                                       \
    }

    // T19: LLVM SchedGroupMask MFMA=0x8, DS_READ=0x100. Group sequence:
    // 12 ks0 reads up front, then {1 read : 2 MFMA} x12 (ks1 reads hidden
    // under ks0 MFMAs), then the remaining 40 MFMA.
#define SGB(mask, n) __builtin_amdgcn_sched_group_barrier(mask, n, 0)
#define SGB_PATTERN                                                          \
    {                                                                        \
        SGB(0x100, 12);                                                      \
        _Pragma("unroll") for (int r_ = 0; r_ < 12; ++r_) {                  \
            SGB(0x100, 1);                                                   \
            SGB(0x8, 2);                                                     \
        }                                                                    \
        SGB(0x8, 40);                                                        \
    }

#define TILE_END                                                             \
    {                                                                        \
        asm volatile("s_waitcnt vmcnt(0)" ::: "memory");                     \
        __builtin_amdgcn_s_barrier();                                        \
        __builtin_amdgcn_sched_barrier(0);                                   \
    }

    // Prologue: stage tile 0 into buf0 (latency exposed once).
    STAGE_TILE(As0, Bs0, 0);
    TILE_END;

#pragma unroll 1
    for (int it = 0; it < 15; ++it) {
        STAGE_TILE(As1, Bs1, 2 * it + 1);
        __builtin_amdgcn_sched_barrier(0);   // pin stage issue before compute
        COMPUTE_TILE(As0, Bs0);
        SGB_PATTERN;
        TILE_END;
        STAGE_TILE(As0, Bs0, 2 * it + 2);
        __builtin_amdgcn_sched_barrier(0);
        COMPUTE_TILE(As1, Bs1);
        SGB_PATTERN;
        TILE_END;
    }
    // Tile 30 (buf0): stage final tile 31 -> buf1.
    STAGE_TILE(As1, Bs1, 31);
    __builtin_amdgcn_sched_barrier(0);
    COMPUTE_TILE(As0, Bs0);
    SGB_PATTERN;
    TILE_END;
    // Tile 31 (buf1): compute only.
    COMPUTE_TILE(As1, Bs1);

    // Epilogue: C/D layout col = lane&15, row = (lane>>4)*4 + reg.
    const int orow = (lane >> 4) * 4;
    const int ocol = lane & 15;
#pragma unroll
    for (int j = 0; j < 4; ++j) {
        const int gn = n0 + wc * 64 + j * 16 + ocol;
        const float bb = beta * (float)bias[gn];
#pragma unroll
        for (int i = 0; i < 8; ++i) {
            const int gm = m0 + wr * 128 + i * 16 + orow;
#pragma unroll
            for (int r = 0; r < 4; ++r) {
                float v = alpha * (float)acc[i][j][r] + bb;
                v = rintf(v);                       // round half-to-even (numpy)
                v = fminf(fmaxf(v, -128.0f), 127.0f);
                out[(size_t)(gm + r) * N_DIM + gn] = (int32_t)v;
            }
        }
    }
}

// ---------------------------------------------------------------------------
extern "C" void kernel_launch(void* const* d_in, const int* in_sizes, int n_in,
                              void* d_out, int out_size, void* d_ws, size_t ws_size,
                              hipStream_t stream) {
    const int*   x    = (const int*)d_in[0];    // [M, K] widened int8
    const int*   w    = (const int*)d_in[1];    // [N, K] widened int8
    const int*   bias = (const int*)d_in[2];    // [N]
    const float* a    = (const float*)d_in[3];  // alpha scalar
    const float* b    = (const float*)d_in[4];  // beta scalar
    int32_t*     out  = (int32_t*)d_out;        // [M, N]

    char* xq = (char*)d_ws;                     // 32 MiB packed x
    const int nx   = (M_DIM * K_DIM) / 4;       // int4-groups in x
    const int nw   = (N_DIM * K_DIM) / 4;
    const int ntot = nx + nw;
    pack_kernel<<<(ntot + 255) / 256, 256, 0, stream>>>(
        (const int4*)x, (const int4*)w, (unsigned int*)xq, nx, ntot);

    char* wq = xq + (size_t)M_DIM * K_DIM;      // 16 MiB packed weight

    dim3 grid((M_DIM / 256) * (N_DIM / 256));   // 512 blocks, 1D for XCD swizzle
    gemm_i8_kernel<<<grid, 512, 0, stream>>>(xq, wq, bias, a, b, out);
}